// Round 3
// baseline (497.185 us; speedup 1.0000x reference)
//
#include <hip/hip_runtime.h>
#include <hip/hip_bf16.h>

#define NB 32
#define NT 1024
#define ND 512
#define NS 1024

#define CTX_ELEMS (32u * 1024u * 512u)          // 16777216
#define SP_SCRATCH_OFF (CTX_ELEMS - 32u*1024u)  // stash sp in contexts tail (overwritten later)

__device__ __forceinline__ float vlog2(float x) {
    float r; asm("v_log_f32 %0, %1" : "=v"(r) : "v"(x)); return r;
}
__device__ __forceinline__ float vexp2(float x) {
    float r; asm("v_exp_f32 %0, %1" : "=v"(r) : "v"(x)); return r;
}
__device__ __forceinline__ float vrcp(float x) {
    float r; asm("v_rcp_f32 %0, %1" : "=v"(r) : "v"(x)); return r;
}

template<int ctrl, int rm, int bm, bool bc>
__device__ __forceinline__ float dppadd(float x) {
    int y = __builtin_amdgcn_update_dpp(0, __float_as_int(x), ctrl, rm, bm, bc);
    return x + __int_as_float(y);
}
// full-wave sum; valid result lands in lane 63
__device__ __forceinline__ float reduce63(float x) {
    x = dppadd<0x111, 0xf, 0xf, true >(x);   // row_shr:1
    x = dppadd<0x112, 0xf, 0xf, true >(x);   // row_shr:2
    x = dppadd<0x114, 0xf, 0xf, true >(x);   // row_shr:4
    x = dppadd<0x118, 0xf, 0xf, true >(x);   // row_shr:8
    x = dppadd<0x142, 0xa, 0xf, false>(x);   // row_bcast:15
    x = dppadd<0x143, 0xc, 0xf, false>(x);   // row_bcast:31
    return x;
}
// lane L receives x from lane L-1 (lane 0 gets 0)
__device__ __forceinline__ float wave_shr1(float x) {
    int y = __builtin_amdgcn_update_dpp(0, __float_as_int(x), 0x138, 0xf, 0xf, true);
    return __int_as_float(y);
}

__device__ __forceinline__ void lds_barrier() {
    asm volatile("s_waitcnt lgkmcnt(0)" ::: "memory");
    __builtin_amdgcn_s_barrier();
    asm volatile("" ::: "memory");
}

// ---------------- kernel 1: sp[b][t] = sigmoid(dot(x[b,t,:], W) + bias) ----------------
__global__ __launch_bounds__(256) void sp_kernel(const float* __restrict__ x,
                                                 const float* __restrict__ W,
                                                 const float* __restrict__ bias,
                                                 float* __restrict__ sp)
{
    const int lane = threadIdx.x & 63;
    const int wid  = threadIdx.x >> 6;
    const int row  = blockIdx.x * 4 + wid;          // b*NT + t
    const float4* xr = reinterpret_cast<const float4*>(x + (size_t)row * ND) + lane * 2;
    const float4* wr = reinterpret_cast<const float4*>(W) + lane * 2;
    float4 xa = xr[0], xb = xr[1];
    float4 wa = wr[0], wb = wr[1];
    float d = xa.x*wa.x + xa.y*wa.y + xa.z*wa.z + xa.w*wa.w
            + xb.x*wb.x + xb.y*wb.y + xb.z*wb.z + xb.w*wb.w;
    #pragma unroll
    for (int m = 1; m < 64; m <<= 1) d += __shfl_xor(d, m);
    if (lane == 0) {
        float z = d + bias[0];
        float e = vexp2(-z * 1.442695040888963f);
        sp[row] = 1.0f / (1.0f + e);
    }
}

// ---------------- kernel 2: sequential scan, 4 waves per batch row ----------------
__global__ __launch_bounds__(256) void scan_kernel(const float* __restrict__ sp,
                                                   float* __restrict__ alphas)
{
    const int b    = blockIdx.x;
    const int tx   = threadIdx.x;
    const int lane = tx & 63;
    const int wid  = tx >> 6;

    // per-wave exchange record: [parity][wave] = {p1, p2, boundary, pad}
    __shared__ __align__(16) float xch[2][4][4];

    float spv0, spv1, spv2, spv3;
    {
        float4 v = *reinterpret_cast<const float4*>(sp + (size_t)b * NT + tx * 4);
        spv0 = v.x; spv1 = v.y; spv2 = v.z; spv3 = v.w;
    }
    float a0 = 1e-7f, a1 = 1e-7f, a2 = 1e-7f, a3 = 1e-7f;
    if (tx == 0) a0 = 1.0f;

    // e_j = shifted_j - a_j for the first step
    float prevn = wave_shr1(a3);
    float carry0 = (wid == 0) ? 0.0f : 1e-7f;
    float e0 = ((lane == 0) ? carry0 : prevn) - a0;
    float e1 = a0 - a1, e2 = a1 - a2, e3 = a2 - a3;

    // initial u = sum(alpha0 * sp), inv = 1 (reference uses raw alpha0)
    {
        float q2 = fmaf(a0, spv0, fmaf(a1, spv1, fmaf(a2, spv2, a3 * spv3)));
        q2 = reduce63(q2);
        if (lane == 63) xch[1][wid][1] = q2;
    }
    lds_barrier();
    float u = (xch[1][0][1] + xch[1][1][1]) + (xch[1][2][1] + xch[1][3][1]);
    float inv = 1.0f;

    float* outp = alphas + (size_t)b * NS * NT + tx * 4;

    for (int s = 0; s < NS; ++s) {
        const int p = s & 1;
        const float sq = 1.7f - fabsf(u - 0.5f);

        // v = inv*(a + u*e) + 1e-6 ; anew = v^sq
        float an0 = vexp2(sq * vlog2(fmaf(inv, fmaf(u, e0, a0), 1e-6f)));
        float an1 = vexp2(sq * vlog2(fmaf(inv, fmaf(u, e1, a1), 1e-6f)));
        float an2 = vexp2(sq * vlog2(fmaf(inv, fmaf(u, e2, a2), 1e-6f)));
        float an3 = vexp2(sq * vlog2(fmaf(inv, fmaf(u, e3, a3), 1e-6f)));

        // off-chain: next-step shift diffs (independent of u_{s+1})
        prevn = wave_shr1(an3);
        float ne1 = an0 - an1, ne2 = an1 - an2, ne3 = an2 - an3;

        // fused partial sums
        float p1 = (an0 + an1) + (an2 + an3);
        float q2 = fmaf(an0, spv0, an1 * spv1) + fmaf(an2, spv2, an3 * spv3);
        p1 = reduce63(p1);
        q2 = reduce63(q2);
        if (lane == 63) {
            float4 rec; rec.x = p1; rec.y = q2; rec.z = an3; rec.w = 0.0f;
            *reinterpret_cast<float4*>(&xch[p][wid][0]) = rec;
        }
        lds_barrier();

        float2 r0 = *reinterpret_cast<const float2*>(&xch[p][0][0]);
        float2 r1 = *reinterpret_cast<const float2*>(&xch[p][1][0]);
        float2 r2 = *reinterpret_cast<const float2*>(&xch[p][2][0]);
        float2 r3 = *reinterpret_cast<const float2*>(&xch[p][3][0]);
        float bnd = xch[p][(wid == 0) ? 0 : (wid - 1)][2];

        float t1 = (r0.x + r1.x) + (r2.x + r3.x);
        float t2 = (r0.y + r1.y) + (r2.y + r3.y);
        inv = vrcp(t1);
        u   = t2 * inv;

        float carry = (wid == 0) ? 0.0f : bnd;
        e0 = ((lane == 0) ? carry : prevn) - an0;
        e1 = ne1; e2 = ne2; e3 = ne3;

        // store normalized alphas (fire-and-forget; no barrier drains vmcnt)
        float4 o;
        o.x = an0 * inv; o.y = an1 * inv; o.z = an2 * inv; o.w = an3 * inv;
        *reinterpret_cast<float4*>(outp) = o;
        outp += NT;

        a0 = an0; a1 = an1; a2 = an2; a3 = an3;
    }
}

// ---------------- kernel 3: contexts[b] = alphas[b] (SxT) @ x[b] (TxD), bf16 MFMA ------
typedef __bf16 bf16x8 __attribute__((ext_vector_type(8)));
typedef float  f32x4  __attribute__((ext_vector_type(4)));

#define BM 128
#define BN 128
#define BK 32
#define LDP 40   // padded leading dim (bf16 elems)

__global__ __launch_bounds__(256) void gemm_kernel(const float* __restrict__ alphas,
                                                   const float* __restrict__ x,
                                                   float* __restrict__ contexts)
{
    __shared__ __align__(16) __bf16 As[BM * LDP];   // As[row][k]
    __shared__ __align__(16) __bf16 Xs[BN * LDP];   // Xs[n][k]  (transposed)

    const int b  = blockIdx.z;
    const int s0 = blockIdx.y * BM;
    const int n0 = blockIdx.x * BN;
    const int tx = threadIdx.x;
    const int lane = tx & 63;
    const int wid  = tx >> 6;
    const int wm = wid >> 1, wn = wid & 1;          // wave tile 64x64
    const int lr = lane & 15;
    const int lk = (lane >> 4) * 8;

    f32x4 acc[4][4];
    #pragma unroll
    for (int i = 0; i < 4; ++i)
        #pragma unroll
        for (int j = 0; j < 4; ++j) acc[i][j] = (f32x4){0.f, 0.f, 0.f, 0.f};

    const int arow = tx >> 1;
    const int akb  = (tx & 1) * 16;
    const int xk0 = tx >> 5;          // 0..7
    const int xn4 = (tx & 31) * 4;    // 0..124

    const float* ap = alphas + ((size_t)b * NS + s0 + arow) * NT + akb;
    const float* xp = x + ((size_t)b * NT + xk0) * ND + n0 + xn4;

    // prologue: load tile 0 into regs
    float4 va0 = reinterpret_cast<const float4*>(ap)[0];
    float4 va1 = reinterpret_cast<const float4*>(ap)[1];
    float4 va2 = reinterpret_cast<const float4*>(ap)[2];
    float4 va3 = reinterpret_cast<const float4*>(ap)[3];
    float4 vx0 = *reinterpret_cast<const float4*>(xp + 0 * 8 * ND);
    float4 vx1 = *reinterpret_cast<const float4*>(xp + 1 * 8 * ND);
    float4 vx2 = *reinterpret_cast<const float4*>(xp + 2 * 8 * ND);
    float4 vx3 = *reinterpret_cast<const float4*>(xp + 3 * 8 * ND);
    ap += BK;
    xp += (size_t)BK * ND;

    for (int k0 = 0; k0 < NT; k0 += BK) {
        // convert + stage current tile from regs
        {
            bf16x8 w0, w1;
            w0[0]=(__bf16)va0.x; w0[1]=(__bf16)va0.y; w0[2]=(__bf16)va0.z; w0[3]=(__bf16)va0.w;
            w0[4]=(__bf16)va1.x; w0[5]=(__bf16)va1.y; w0[6]=(__bf16)va1.z; w0[7]=(__bf16)va1.w;
            w1[0]=(__bf16)va2.x; w1[1]=(__bf16)va2.y; w1[2]=(__bf16)va2.z; w1[3]=(__bf16)va2.w;
            w1[4]=(__bf16)va3.x; w1[5]=(__bf16)va3.y; w1[6]=(__bf16)va3.z; w1[7]=(__bf16)va3.w;
            *reinterpret_cast<bf16x8*>(&As[arow * LDP + akb])     = w0;
            *reinterpret_cast<bf16x8*>(&As[arow * LDP + akb + 8]) = w1;
            int kk0 = xk0;
            Xs[(xn4+0)*LDP + kk0]      = (__bf16)vx0.x;
            Xs[(xn4+1)*LDP + kk0]      = (__bf16)vx0.y;
            Xs[(xn4+2)*LDP + kk0]      = (__bf16)vx0.z;
            Xs[(xn4+3)*LDP + kk0]      = (__bf16)vx0.w;
            Xs[(xn4+0)*LDP + kk0 + 8]  = (__bf16)vx1.x;
            Xs[(xn4+1)*LDP + kk0 + 8]  = (__bf16)vx1.y;
            Xs[(xn4+2)*LDP + kk0 + 8]  = (__bf16)vx1.z;
            Xs[(xn4+3)*LDP + kk0 + 8]  = (__bf16)vx1.w;
            Xs[(xn4+0)*LDP + kk0 + 16] = (__bf16)vx2.x;
            Xs[(xn4+1)*LDP + kk0 + 16] = (__bf16)vx2.y;
            Xs[(xn4+2)*LDP + kk0 + 16] = (__bf16)vx2.z;
            Xs[(xn4+3)*LDP + kk0 + 16] = (__bf16)vx2.w;
            Xs[(xn4+0)*LDP + kk0 + 24] = (__bf16)vx3.x;
            Xs[(xn4+1)*LDP + kk0 + 24] = (__bf16)vx3.y;
            Xs[(xn4+2)*LDP + kk0 + 24] = (__bf16)vx3.z;
            Xs[(xn4+3)*LDP + kk0 + 24] = (__bf16)vx3.w;
        }
        // issue next tile's loads BEFORE the barrier — they stay in flight across it
        if (k0 + BK < NT) {
            va0 = reinterpret_cast<const float4*>(ap)[0];
            va1 = reinterpret_cast<const float4*>(ap)[1];
            va2 = reinterpret_cast<const float4*>(ap)[2];
            va3 = reinterpret_cast<const float4*>(ap)[3];
            vx0 = *reinterpret_cast<const float4*>(xp + 0 * 8 * ND);
            vx1 = *reinterpret_cast<const float4*>(xp + 1 * 8 * ND);
            vx2 = *reinterpret_cast<const float4*>(xp + 2 * 8 * ND);
            vx3 = *reinterpret_cast<const float4*>(xp + 3 * 8 * ND);
            ap += BK;
            xp += (size_t)BK * ND;
        }
        lds_barrier();   // lgkmcnt only — prefetch loads NOT drained

        bf16x8 av[4], bv[4];
        #pragma unroll
        for (int i = 0; i < 4; ++i)
            av[i] = *reinterpret_cast<const bf16x8*>(&As[(wm*64 + i*16 + lr) * LDP + lk]);
        #pragma unroll
        for (int j = 0; j < 4; ++j)
            bv[j] = *reinterpret_cast<const bf16x8*>(&Xs[(wn*64 + j*16 + lr) * LDP + lk]);
        #pragma unroll
        for (int i = 0; i < 4; ++i)
            #pragma unroll
            for (int j = 0; j < 4; ++j)
                acc[i][j] = __builtin_amdgcn_mfma_f32_16x16x32_bf16(av[i], bv[j], acc[i][j], 0, 0, 0);
        lds_barrier();
    }

    const int ccol = lr;
    const int crow = (lane >> 4) * 4;
    #pragma unroll
    for (int i = 0; i < 4; ++i) {
        #pragma unroll
        for (int j = 0; j < 4; ++j) {
            int col = n0 + wn*64 + j*16 + ccol;
            int rb2 = s0 + wm*64 + i*16 + crow;
            #pragma unroll
            for (int r = 0; r < 4; ++r)
                contexts[((size_t)b * NS + rb2 + r) * ND + col] = acc[i][j][r];
        }
    }
}

extern "C" void kernel_launch(void* const* d_in, const int* in_sizes, int n_in,
                              void* d_out, int out_size, void* d_ws, size_t ws_size,
                              hipStream_t stream) {
    const float* x    = (const float*)d_in[0];
    const float* W    = (const float*)d_in[1];
    const float* bias = (const float*)d_in[2];
    float* contexts = (float*)d_out;
    float* alphas   = (float*)d_out + CTX_ELEMS;
    float* sp       = (float*)d_out + SP_SCRATCH_OFF;

    sp_kernel<<<dim3(NB * NT / 4), dim3(256), 0, stream>>>(x, W, bias, sp);
    scan_kernel<<<dim3(NB), dim3(256), 0, stream>>>(sp, alphas);
    gemm_kernel<<<dim3(ND / BN, NS / BM, NB), dim3(256), 0, stream>>>(alphas, x, contexts);
}

// Round 4
// 398.273 us; speedup vs baseline: 1.2484x; 1.2484x over previous
//
#include <hip/hip_runtime.h>
#include <hip/hip_bf16.h>

#define NB 32
#define NT 1024
#define ND 512
#define NS 1024

#define CTX_ELEMS (32u * 1024u * 512u)          // 16777216
#define SP_SCRATCH_OFF (CTX_ELEMS - 32u*1024u)  // stash sp in contexts tail (overwritten later)

__device__ __forceinline__ float vlog2(float x) {
    float r; asm("v_log_f32 %0, %1" : "=v"(r) : "v"(x)); return r;
}
__device__ __forceinline__ float vexp2(float x) {
    float r; asm("v_exp_f32 %0, %1" : "=v"(r) : "v"(x)); return r;
}
__device__ __forceinline__ float vrcp(float x) {
    float r; asm("v_rcp_f32 %0, %1" : "=v"(r) : "v"(x)); return r;
}

template<int ctrl, int rm, int bm, bool bc>
__device__ __forceinline__ float dppadd(float x) {
    int y = __builtin_amdgcn_update_dpp(0, __float_as_int(x), ctrl, rm, bm, bc);
    return x + __int_as_float(y);
}
// full-wave sum; valid result lands in lane 63
__device__ __forceinline__ float reduce63(float x) {
    x = dppadd<0x111, 0xf, 0xf, true >(x);   // row_shr:1
    x = dppadd<0x112, 0xf, 0xf, true >(x);   // row_shr:2
    x = dppadd<0x114, 0xf, 0xf, true >(x);   // row_shr:4
    x = dppadd<0x118, 0xf, 0xf, true >(x);   // row_shr:8
    x = dppadd<0x142, 0xa, 0xf, false>(x);   // row_bcast:15
    x = dppadd<0x143, 0xc, 0xf, false>(x);   // row_bcast:31
    return x;
}
// lane L receives x from lane L-1 (lane 0 gets 0)
__device__ __forceinline__ float wave_shr1(float x) {
    int y = __builtin_amdgcn_update_dpp(0, __float_as_int(x), 0x138, 0xf, 0xf, true);
    return __int_as_float(y);
}

__device__ __forceinline__ void lds_barrier() {
    asm volatile("s_waitcnt lgkmcnt(0)" ::: "memory");
    __builtin_amdgcn_s_barrier();
    asm volatile("" ::: "memory");
}

// ---------------- kernel 1: sp[b][t] = sigmoid(dot(x[b,t,:], W) + bias) ----------------
__global__ __launch_bounds__(256) void sp_kernel(const float* __restrict__ x,
                                                 const float* __restrict__ W,
                                                 const float* __restrict__ bias,
                                                 float* __restrict__ sp)
{
    const int lane = threadIdx.x & 63;
    const int wid  = threadIdx.x >> 6;
    const int row  = blockIdx.x * 4 + wid;          // b*NT + t
    const float4* xr = reinterpret_cast<const float4*>(x + (size_t)row * ND) + lane * 2;
    const float4* wr = reinterpret_cast<const float4*>(W) + lane * 2;
    float4 xa = xr[0], xb = xr[1];
    float4 wa = wr[0], wb = wr[1];
    float d = xa.x*wa.x + xa.y*wa.y + xa.z*wa.z + xa.w*wa.w
            + xb.x*wb.x + xb.y*wb.y + xb.z*wb.z + xb.w*wb.w;
    #pragma unroll
    for (int m = 1; m < 64; m <<= 1) d += __shfl_xor(d, m);
    if (lane == 0) {
        float z = d + bias[0];
        float e = vexp2(-z * 1.442695040888963f);
        sp[row] = 1.0f / (1.0f + e);
    }
}

// ---------------- kernel 2: sequential scan, 4 waves per batch row (R2 structure) ------
__global__ __launch_bounds__(256) void scan_kernel(const float* __restrict__ sp,
                                                   float* __restrict__ alphas)
{
    const int b    = blockIdx.x;
    const int tx   = threadIdx.x;
    const int lane = tx & 63;
    const int wid  = tx >> 6;

    __shared__ float r1[2][4];   // per-wave partial sum(a)
    __shared__ float r2[2][4];   // per-wave partial sum(a*sp)
    __shared__ float rb[2][4];   // per-wave boundary value (unnormalized a at t = w*256+255)

    float spv[4], raw[4];
    {
        float4 v = *reinterpret_cast<const float4*>(sp + (size_t)b * NT + tx * 4);
        spv[0] = v.x; spv[1] = v.y; spv[2] = v.z; spv[3] = v.w;
    }
    #pragma unroll
    for (int j = 0; j < 4; ++j) raw[j] = 1e-7f;
    if (tx == 0) raw[0] = 1.0f;
    float carry = (wid == 0) ? 0.0f : 1e-7f;        // alpha value at t = w*256 - 1

    // initial u = sum(alpha0 * sp), alpha0 raw (matches reference), inv = 1
    {
        float p2 = fmaf(raw[0], spv[0], fmaf(raw[1], spv[1], fmaf(raw[2], spv[2], raw[3]*spv[3])));
        p2 = reduce63(p2);
        if (lane == 63) r2[1][wid] = p2;
    }
    __syncthreads();
    float u;
    {
        float4 v2 = *reinterpret_cast<const float4*>(r2[1]);
        u = (v2.x + v2.y) + (v2.z + v2.w);
    }
    float inv = 1.0f;

    float* outp = alphas + (size_t)b * NS * NT + tx * 4;

    for (int s = 0; s < NS; ++s) {
        const int p = s & 1;
        const float sq = 1.7f - fabsf(u - 0.5f);
        const float c1 = (1.0f - u) * inv;          // multiplies raw (unnormalized)
        const float c0 = u * inv;                   // multiplies shifted (unnormalized)

        float prev = wave_shr1(raw[3]);
        float sh0  = (lane == 0) ? carry : prev;

        float anew[4];
        {
            float v0 = fmaf(c1, raw[0], fmaf(c0, sh0,    1e-6f));
            float v1 = fmaf(c1, raw[1], fmaf(c0, raw[0], 1e-6f));
            float v2 = fmaf(c1, raw[2], fmaf(c0, raw[1], 1e-6f));
            float v3 = fmaf(c1, raw[3], fmaf(c0, raw[2], 1e-6f));
            anew[0] = vexp2(sq * vlog2(v0));
            anew[1] = vexp2(sq * vlog2(v1));
            anew[2] = vexp2(sq * vlog2(v2));
            anew[3] = vexp2(sq * vlog2(v3));
        }

        float p1 = (anew[0] + anew[1]) + (anew[2] + anew[3]);
        float p2 = fmaf(anew[0], spv[0], anew[1]*spv[1]) + fmaf(anew[2], spv[2], anew[3]*spv[3]);
        p1 = reduce63(p1);
        p2 = reduce63(p2);
        if (lane == 63) { r1[p][wid] = p1; r2[p][wid] = p2; rb[p][wid] = anew[3]; }
        __syncthreads();

        float4 v1 = *reinterpret_cast<const float4*>(r1[p]);
        float4 v2 = *reinterpret_cast<const float4*>(r2[p]);
        float bc  = rb[p][(wid == 0) ? 0 : (wid - 1)];
        carry = (wid == 0) ? 0.0f : bc;

        float t1 = (v1.x + v1.y) + (v1.z + v1.w);
        float t2 = (v2.x + v2.y) + (v2.z + v2.w);
        inv = vrcp(t1);
        u   = t2 * inv;

        float4 o;
        o.x = anew[0] * inv; o.y = anew[1] * inv; o.z = anew[2] * inv; o.w = anew[3] * inv;
        *reinterpret_cast<float4*>(outp + (size_t)s * NT) = o;

        #pragma unroll
        for (int j = 0; j < 4; ++j) raw[j] = anew[j];
    }
}

// ---------------- kernel 3: contexts[b] = alphas[b] (SxT) @ x[b] (TxD), bf16 MFMA ------
// 256x256 tile, 512 threads = 8 waves (2 x 4), each wave owns 128x64
typedef __bf16 bf16x8 __attribute__((ext_vector_type(8)));
typedef float  f32x4  __attribute__((ext_vector_type(4)));

#define BM 256
#define BN 256
#define BK 32
#define LDP 40   // padded leading dim (bf16 elems)

__global__ __launch_bounds__(512, 2) void gemm_kernel(const float* __restrict__ alphas,
                                                      const float* __restrict__ x,
                                                      float* __restrict__ contexts)
{
    __shared__ __align__(16) __bf16 As[BM * LDP];   // As[row][k]   20 KB
    __shared__ __align__(16) __bf16 Xs[BN * LDP];   // Xs[n][k]     20 KB (transposed)

    const int b  = blockIdx.z;
    const int s0 = blockIdx.y * BM;
    const int n0 = blockIdx.x * BN;
    const int tx = threadIdx.x;
    const int lane = tx & 63;
    const int wid  = tx >> 6;
    const int wm = wid >> 2;          // 0..1  (128-row slab)
    const int wn = wid & 3;           // 0..3  (64-col slab)
    const int lr = lane & 15;
    const int lk = (lane >> 4) * 8;

    f32x4 acc[8][4];
    #pragma unroll
    for (int i = 0; i < 8; ++i)
        #pragma unroll
        for (int j = 0; j < 4; ++j) acc[i][j] = (f32x4){0.f, 0.f, 0.f, 0.f};

    // A staging map: 2 threads per row (256 rows), 16 f32 each
    const int arow = tx >> 1;
    const int akb  = (tx & 1) * 16;
    // X staging map: 8 k-rows per pass (tx>>6), 64 threads cover 256 cols (4 each)
    const int xk0 = tx >> 6;          // 0..7
    const int xn4 = (tx & 63) * 4;    // 0..252

    const float* ap = alphas + ((size_t)b * NS + s0 + arow) * NT + akb;
    const float* xp = x + ((size_t)b * NT + xk0) * ND + n0 + xn4;

    // prologue: load tile 0 into regs
    float4 va0 = reinterpret_cast<const float4*>(ap)[0];
    float4 va1 = reinterpret_cast<const float4*>(ap)[1];
    float4 va2 = reinterpret_cast<const float4*>(ap)[2];
    float4 va3 = reinterpret_cast<const float4*>(ap)[3];
    float4 vx0 = *reinterpret_cast<const float4*>(xp + 0 * 8 * ND);
    float4 vx1 = *reinterpret_cast<const float4*>(xp + 1 * 8 * ND);
    float4 vx2 = *reinterpret_cast<const float4*>(xp + 2 * 8 * ND);
    float4 vx3 = *reinterpret_cast<const float4*>(xp + 3 * 8 * ND);
    ap += BK;
    xp += (size_t)BK * ND;

    for (int k0 = 0; k0 < NT; k0 += BK) {
        // convert + stage current tile from regs
        {
            bf16x8 w0, w1;
            w0[0]=(__bf16)va0.x; w0[1]=(__bf16)va0.y; w0[2]=(__bf16)va0.z; w0[3]=(__bf16)va0.w;
            w0[4]=(__bf16)va1.x; w0[5]=(__bf16)va1.y; w0[6]=(__bf16)va1.z; w0[7]=(__bf16)va1.w;
            w1[0]=(__bf16)va2.x; w1[1]=(__bf16)va2.y; w1[2]=(__bf16)va2.z; w1[3]=(__bf16)va2.w;
            w1[4]=(__bf16)va3.x; w1[5]=(__bf16)va3.y; w1[6]=(__bf16)va3.z; w1[7]=(__bf16)va3.w;
            *reinterpret_cast<bf16x8*>(&As[arow * LDP + akb])     = w0;
            *reinterpret_cast<bf16x8*>(&As[arow * LDP + akb + 8]) = w1;
            Xs[(xn4+0)*LDP + xk0]      = (__bf16)vx0.x;
            Xs[(xn4+1)*LDP + xk0]      = (__bf16)vx0.y;
            Xs[(xn4+2)*LDP + xk0]      = (__bf16)vx0.z;
            Xs[(xn4+3)*LDP + xk0]      = (__bf16)vx0.w;
            Xs[(xn4+0)*LDP + xk0 + 8]  = (__bf16)vx1.x;
            Xs[(xn4+1)*LDP + xk0 + 8]  = (__bf16)vx1.y;
            Xs[(xn4+2)*LDP + xk0 + 8]  = (__bf16)vx1.z;
            Xs[(xn4+3)*LDP + xk0 + 8]  = (__bf16)vx1.w;
            Xs[(xn4+0)*LDP + xk0 + 16] = (__bf16)vx2.x;
            Xs[(xn4+1)*LDP + xk0 + 16] = (__bf16)vx2.y;
            Xs[(xn4+2)*LDP + xk0 + 16] = (__bf16)vx2.z;
            Xs[(xn4+3)*LDP + xk0 + 16] = (__bf16)vx2.w;
            Xs[(xn4+0)*LDP + xk0 + 24] = (__bf16)vx3.x;
            Xs[(xn4+1)*LDP + xk0 + 24] = (__bf16)vx3.y;
            Xs[(xn4+2)*LDP + xk0 + 24] = (__bf16)vx3.z;
            Xs[(xn4+3)*LDP + xk0 + 24] = (__bf16)vx3.w;
        }
        // issue next tile's loads BEFORE the barrier — stay in flight across it
        if (k0 + BK < NT) {
            va0 = reinterpret_cast<const float4*>(ap)[0];
            va1 = reinterpret_cast<const float4*>(ap)[1];
            va2 = reinterpret_cast<const float4*>(ap)[2];
            va3 = reinterpret_cast<const float4*>(ap)[3];
            vx0 = *reinterpret_cast<const float4*>(xp + 0 * 8 * ND);
            vx1 = *reinterpret_cast<const float4*>(xp + 1 * 8 * ND);
            vx2 = *reinterpret_cast<const float4*>(xp + 2 * 8 * ND);
            vx3 = *reinterpret_cast<const float4*>(xp + 3 * 8 * ND);
            ap += BK;
            xp += (size_t)BK * ND;
        }
        lds_barrier();   // lgkmcnt only — prefetch global loads NOT drained

        bf16x8 av[8], bv[4];
        #pragma unroll
        for (int j = 0; j < 4; ++j)
            bv[j] = *reinterpret_cast<const bf16x8*>(&Xs[(wn*64 + j*16 + lr) * LDP + lk]);
        #pragma unroll
        for (int i = 0; i < 8; ++i)
            av[i] = *reinterpret_cast<const bf16x8*>(&As[(wm*128 + i*16 + lr) * LDP + lk]);
        #pragma unroll
        for (int i = 0; i < 8; ++i)
            #pragma unroll
            for (int j = 0; j < 4; ++j)
                acc[i][j] = __builtin_amdgcn_mfma_f32_16x16x32_bf16(av[i], bv[j], acc[i][j], 0, 0, 0);
        lds_barrier();
    }

    const int ccol = lr;
    const int crow = (lane >> 4) * 4;
    #pragma unroll
    for (int i = 0; i < 8; ++i) {
        #pragma unroll
        for (int j = 0; j < 4; ++j) {
            int col = n0 + wn*64 + j*16 + ccol;
            int rw  = s0 + wm*128 + i*16 + crow;
            #pragma unroll
            for (int r = 0; r < 4; ++r)
                contexts[((size_t)b * NS + rw + r) * ND + col] = acc[i][j][r];
        }
    }
}

extern "C" void kernel_launch(void* const* d_in, const int* in_sizes, int n_in,
                              void* d_out, int out_size, void* d_ws, size_t ws_size,
                              hipStream_t stream) {
    const float* x    = (const float*)d_in[0];
    const float* W    = (const float*)d_in[1];
    const float* bias = (const float*)d_in[2];
    float* contexts = (float*)d_out;
    float* alphas   = (float*)d_out + CTX_ELEMS;
    float* sp       = (float*)d_out + SP_SCRATCH_OFF;

    sp_kernel<<<dim3(NB * NT / 4), dim3(256), 0, stream>>>(x, W, bias, sp);
    scan_kernel<<<dim3(NB), dim3(256), 0, stream>>>(sp, alphas);
    gemm_kernel<<<dim3(ND / BN, NS / BM, NB), dim3(512), 0, stream>>>(alphas, x, contexts);
}